// Round 1
// baseline (729.562 us; speedup 1.0000x reference)
//
#include <hip/hip_runtime.h>
#include <cstdint>
#include <cstddef>

#define S_LEN 2048
#define D_MODEL 2048
#define NH 32
#define NKV 8
#define HD_ 64
#define BATCH 2
#define KVD 512

typedef float f32x4 __attribute__((ext_vector_type(4)));
typedef short s16x8 __attribute__((ext_vector_type(8)));

__device__ __forceinline__ unsigned short f2bf(float f) {
  unsigned int u = __builtin_bit_cast(unsigned int, f);
  u = (u + 0x7fffu + ((u >> 16) & 1u)) >> 16;
  return (unsigned short)u;
}
__device__ __forceinline__ float bf2f(unsigned short h) {
  return __builtin_bit_cast(float, ((unsigned int)h) << 16);
}

// ---------------- f32 -> bf16 convert (vectorized x4) ----------------
__global__ void cvt_kernel(const float* __restrict__ in, unsigned short* __restrict__ out, int n4) {
  int i = blockIdx.x * blockDim.x + threadIdx.x;
  if (i >= n4) return;
  float4 v = reinterpret_cast<const float4*>(in)[i];
  ushort4 o;
  o.x = f2bf(v.x); o.y = f2bf(v.y); o.z = f2bf(v.z); o.w = f2bf(v.w);
  reinterpret_cast<ushort4*>(out)[i] = o;
}

// ---------------- RoPE in-place on bf16 buffer [B*S][nheads*64] ----------------
__global__ void rope_kernel(unsigned short* __restrict__ buf, const float* __restrict__ cosb,
                            const float* __restrict__ sinb, int nheads, int total) {
  int i = blockIdx.x * blockDim.x + threadIdx.x;
  if (i >= total) return;
  int pair = i & 31;              // 0..31 (HD/2)
  int rest = i >> 5;              // (b*S + s)*nheads + head
  int s = (rest / nheads) % S_LEN;
  float c = cosb[s * 32 + pair], sn = sinb[s * 32 + pair];
  size_t base = (size_t)rest * HD_ + (size_t)pair * 2;
  float r  = bf2f(buf[base]);
  float im = bf2f(buf[base + 1]);
  buf[base]     = f2bf(r * c - im * sn);
  buf[base + 1] = f2bf(r * sn + im * c);
}

// ---------------- GEMM: C[m][n] = sum_k A[m][k] * W[n][k], bf16 in, f32 acc ----------------
// BM=BN=128, BK=32. 256 threads = 4 waves in 2x2, each wave 64x64 (4x4 frags of 16x16).
#define GBM 128
#define GBN 128
#define GBK 32
#define LDSK 40   // 32 elems + 8 pad -> 80B row stride (16B aligned, 2-way bank alias = free)

template<int OUTF32>
__global__ __launch_bounds__(256) void gemm_bt(const unsigned short* __restrict__ A,
                                               const unsigned short* __restrict__ W,
                                               float* __restrict__ Cf,
                                               unsigned short* __restrict__ Cb,
                                               int M, int N, int K) {
  __shared__ alignas(16) short As[GBM][LDSK];
  __shared__ alignas(16) short Bs[GBN][LDSK];
  int tid = threadIdx.x;
  int lane = tid & 63, wid = tid >> 6;
  int m0 = blockIdx.y * GBM;
  int n0 = blockIdx.x * GBN;
  int wm = (wid >> 1) * 64, wn = (wid & 1) * 64;
  int lrow = lane & 15, lk = lane >> 4;
  f32x4 acc[4][4] = {};

  for (int k0 = 0; k0 < K; k0 += GBK) {
    __syncthreads();
    // stage A and B tiles: 128x32 bf16 each = 8KB; 256 threads x 2 chunks x 16B
#pragma unroll
    for (int j = 0; j < 2; ++j) {
      int chunk = tid + j * 256;
      int row = chunk >> 2;            // 4 x 16B chunks per 32-elem row
      int cc = (chunk & 3) * 8;
      s16x8 va = *reinterpret_cast<const s16x8*>(A + (size_t)(m0 + row) * K + k0 + cc);
      *reinterpret_cast<s16x8*>(&As[row][cc]) = va;
      s16x8 vb = *reinterpret_cast<const s16x8*>(W + (size_t)(n0 + row) * K + k0 + cc);
      *reinterpret_cast<s16x8*>(&Bs[row][cc]) = vb;
    }
    __syncthreads();
    s16x8 af[4], bfr[4];
#pragma unroll
    for (int mi = 0; mi < 4; ++mi)
      af[mi] = *reinterpret_cast<const s16x8*>(&As[wm + mi * 16 + lrow][lk * 8]);
#pragma unroll
    for (int ni = 0; ni < 4; ++ni)
      bfr[ni] = *reinterpret_cast<const s16x8*>(&Bs[wn + ni * 16 + lrow][lk * 8]);
#pragma unroll
    for (int mi = 0; mi < 4; ++mi)
#pragma unroll
      for (int ni = 0; ni < 4; ++ni)
        acc[mi][ni] = __builtin_amdgcn_mfma_f32_16x16x32_bf16(af[mi], bfr[ni], acc[mi][ni], 0, 0, 0);
  }

  // epilogue: C/D layout col=lane&15, row=(lane>>4)*4+r
#pragma unroll
  for (int mi = 0; mi < 4; ++mi) {
#pragma unroll
    for (int ni = 0; ni < 4; ++ni) {
#pragma unroll
      for (int r = 0; r < 4; ++r) {
        int row = m0 + wm + mi * 16 + lk * 4 + r;
        int col = n0 + wn + ni * 16 + lrow;
        float v = acc[mi][ni][r];
        if (OUTF32) Cf[(size_t)row * N + col] = v;
        else        Cb[(size_t)row * N + col] = f2bf(v);
      }
    }
  }
}

// ---------------- Flash attention (causal, GQA rep=4) ----------------
// grid (S/64, B*H); 256 threads = 4 waves, each wave owns 16 q-rows. KV tile = 32.
#define QBLK 64
#define KVB 32

__global__ __launch_bounds__(256) void attn_kernel(const unsigned short* __restrict__ Q,
                                                   const unsigned short* __restrict__ Kb,
                                                   const unsigned short* __restrict__ Vb,
                                                   unsigned short* __restrict__ O) {
  __shared__ alignas(16) short Ks[32 * 64];      // [kv][d], 128B rows, XOR-swizzled
  __shared__ alignas(16) short Vs[64 * 64];      // transposed [hd][kv], 128B rows, swizzled
  __shared__ alignas(16) short Ps[4][16 * 64];   // per-wave P, 128B rows, swizzled

  int tid = threadIdx.x, lane = tid & 63, wid = tid >> 6;
  int bh = blockIdx.y;
  int b = bh / NH, h = bh % NH, kvh = h >> 2;
  int q0 = blockIdx.x * QBLK;
  int q0w = q0 + wid * 16;
  int lrow = lane & 15, lk = lane >> 4;

  // Q fragments (row=lane&15, k=8*(lane>>4)+j), two 32-wide k-steps cover HD=64
  const unsigned short* qptr = Q + ((size_t)(b * S_LEN) + q0w + lrow) * D_MODEL + h * HD_;
  s16x8 qf0 = *reinterpret_cast<const s16x8*>(qptr + lk * 8);
  s16x8 qf1 = *reinterpret_cast<const s16x8*>(qptr + 32 + lk * 8);

  f32x4 o_acc[4] = {};
  float mrow[4], lsum[4];
#pragma unroll
  for (int r = 0; r < 4; ++r) { mrow[r] = -INFINITY; lsum[r] = 0.f; }

  int nt = (q0 + QBLK) / KVB;
  for (int t = 0; t < nt; ++t) {
    int kv0 = t * KVB;
    __syncthreads();
    {
      // stage K tile [32][64] (4KB): thread -> row=tid/8, 16B chunk (tid%8)
      int row = tid >> 3;
      int cb = (tid & 7) * 16;   // byte col
      s16x8 kvv = *reinterpret_cast<const s16x8*>(
          Kb + ((size_t)(b * S_LEN) + kv0 + row) * KVD + kvh * HD_ + (cb >> 1));
      *reinterpret_cast<s16x8*>((char*)Ks + row * 128 + (cb ^ ((row & 7) << 4))) = kvv;
      // stage V transposed: Vt[hd][kv]
      int vrow = tid >> 3;          // kv index
      int hc = (tid & 7) * 8;       // hd base
      s16x8 vv = *reinterpret_cast<const s16x8*>(
          Vb + ((size_t)(b * S_LEN) + kv0 + vrow) * KVD + kvh * HD_ + hc);
#pragma unroll
      for (int e = 0; e < 8; ++e) {
        int n = hc + e;
        *reinterpret_cast<short*>((char*)Vs + n * 128 + ((vrow * 2) ^ ((n & 7) << 4))) = vv[e];
      }
    }
    __syncthreads();

    // QK^T : two 16-col subtiles, K=64 via 2 MFMAs each
    float sc[2][4];
#pragma unroll
    for (int ct = 0; ct < 2; ++ct) {
      int c = ct * 16 + lrow;   // kv-local col
      s16x8 bk0 = *reinterpret_cast<const s16x8*>((char*)Ks + c * 128 + ((lk * 16) ^ ((c & 7) << 4)));
      s16x8 bk1 = *reinterpret_cast<const s16x8*>((char*)Ks + c * 128 + ((64 + lk * 16) ^ ((c & 7) << 4)));
      f32x4 s = {};
      s = __builtin_amdgcn_mfma_f32_16x16x32_bf16(qf0, bk0, s, 0, 0, 0);
      s = __builtin_amdgcn_mfma_f32_16x16x32_bf16(qf1, bk1, s, 0, 0, 0);
#pragma unroll
      for (int r = 0; r < 4; ++r) {
        int rg = q0w + lk * 4 + r;
        int cg = kv0 + ct * 16 + lrow;
        float v = s[r] * 0.125f;
        sc[ct][r] = (cg > rg) ? -1e30f : v;
      }
    }
    // online softmax per row (rows live in 16-lane groups)
#pragma unroll
    for (int r = 0; r < 4; ++r) {
      float pm = fmaxf(sc[0][r], sc[1][r]);
#pragma unroll
      for (int off = 1; off < 16; off <<= 1) pm = fmaxf(pm, __shfl_xor(pm, off, 64));
      float mnew = fmaxf(mrow[r], pm);
      float alpha = __expf(mrow[r] - mnew);
      mrow[r] = mnew;
      float p0 = __expf(sc[0][r] - mnew);
      float p1 = __expf(sc[1][r] - mnew);
      sc[0][r] = p0; sc[1][r] = p1;
      float ps = p0 + p1;
#pragma unroll
      for (int off = 1; off < 16; off <<= 1) ps += __shfl_xor(ps, off, 64);
      lsum[r] = lsum[r] * alpha + ps;
#pragma unroll
      for (int tt = 0; tt < 4; ++tt) o_acc[tt][r] *= alpha;
    }
    // P (C-layout) -> LDS bf16 (swizzled), then re-read as A-fragments
    char* pw = (char*)Ps[wid];
#pragma unroll
    for (int ct = 0; ct < 2; ++ct)
#pragma unroll
      for (int r = 0; r < 4; ++r) {
        int prow = lk * 4 + r;
        int pcb = (ct * 16 + lrow) * 2;
        *reinterpret_cast<short*>(pw + prow * 128 + (pcb ^ ((prow & 7) << 4))) = (short)f2bf(sc[ct][r]);
      }
    __syncthreads();
    s16x8 pa = *reinterpret_cast<const s16x8*>(pw + lrow * 128 + ((lk * 16) ^ ((lrow & 7) << 4)));
#pragma unroll
    for (int tt = 0; tt < 4; ++tt) {
      int n = tt * 16 + lrow;   // hd col
      s16x8 bv = *reinterpret_cast<const s16x8*>((char*)Vs + n * 128 + ((lk * 16) ^ ((n & 7) << 4)));
      o_acc[tt] = __builtin_amdgcn_mfma_f32_16x16x32_bf16(pa, bv, o_acc[tt], 0, 0, 0);
    }
  }

  // epilogue: O[b][q][h*64+hd] bf16
#pragma unroll
  for (int tt = 0; tt < 4; ++tt)
#pragma unroll
    for (int r = 0; r < 4; ++r) {
      int rg = q0w + lk * 4 + r;
      int col = h * HD_ + tt * 16 + lrow;
      float v = o_acc[tt][r] / lsum[r];
      O[((size_t)(b * S_LEN) + rg) * D_MODEL + col] = f2bf(v);
    }
}

// ---------------- launch ----------------
extern "C" void kernel_launch(void* const* d_in, const int* in_sizes, int n_in,
                              void* d_out, int out_size, void* d_ws, size_t ws_size,
                              hipStream_t stream) {
  const float* x  = (const float*)d_in[0];
  const float* fc = (const float*)d_in[1];
  const float* fs = (const float*)d_in[2];
  const float* wq = (const float*)d_in[3];
  const float* wk = (const float*)d_in[4];
  const float* wv = (const float*)d_in[5];
  const float* wo = (const float*)d_in[6];
  float* out = (float*)d_out;

  const size_t nx  = (size_t)BATCH * S_LEN * D_MODEL;   // 8388608
  const size_t nw  = (size_t)D_MODEL * D_MODEL;         // 4194304
  const size_t nwk = (size_t)KVD * D_MODEL;             // 1048576
  const size_t nkv = (size_t)BATCH * S_LEN * KVD;       // 2097152

  char* ws = (char*)d_ws;
  unsigned short* xb  = (unsigned short*)ws;                 ws += nx  * 2;
  unsigned short* wqb = (unsigned short*)ws;                 ws += nw  * 2;
  unsigned short* wkb = (unsigned short*)ws;                 ws += nwk * 2;
  unsigned short* wvb = (unsigned short*)ws;                 ws += nwk * 2;
  unsigned short* wob = (unsigned short*)ws;                 ws += nw  * 2;
  unsigned short* qb  = (unsigned short*)ws;                 ws += nx  * 2;
  unsigned short* kb  = (unsigned short*)ws;                 ws += nkv * 2;
  unsigned short* vb  = (unsigned short*)ws;                 ws += nkv * 2;
  unsigned short* ab  = (unsigned short*)ws;                 ws += nx  * 2;

  // 1. convert inputs to bf16
  cvt_kernel<<<dim3((nx / 4 + 255) / 256), dim3(256), 0, stream>>>(x, xb, nx / 4);
  cvt_kernel<<<dim3((nw / 4 + 255) / 256), dim3(256), 0, stream>>>(wq, wqb, nw / 4);
  cvt_kernel<<<dim3((nwk / 4 + 255) / 256), dim3(256), 0, stream>>>(wk, wkb, nwk / 4);
  cvt_kernel<<<dim3((nwk / 4 + 255) / 256), dim3(256), 0, stream>>>(wv, wvb, nwk / 4);
  cvt_kernel<<<dim3((nw / 4 + 255) / 256), dim3(256), 0, stream>>>(wo, wob, nw / 4);

  const int M = BATCH * S_LEN;  // 4096
  // 2. projections
  gemm_bt<0><<<dim3(D_MODEL / GBN, M / GBM), dim3(256), 0, stream>>>(xb, wqb, nullptr, qb, M, D_MODEL, D_MODEL);
  gemm_bt<0><<<dim3(KVD / GBN, M / GBM), dim3(256), 0, stream>>>(xb, wkb, nullptr, kb, M, KVD, D_MODEL);
  gemm_bt<0><<<dim3(KVD / GBN, M / GBM), dim3(256), 0, stream>>>(xb, wvb, nullptr, vb, M, KVD, D_MODEL);

  // 3. RoPE on q and k
  {
    int totq = BATCH * S_LEN * NH * 32;
    int totk = BATCH * S_LEN * NKV * 32;
    rope_kernel<<<dim3((totq + 255) / 256), dim3(256), 0, stream>>>(qb, fc, fs, NH, totq);
    rope_kernel<<<dim3((totk + 255) / 256), dim3(256), 0, stream>>>(kb, fc, fs, NKV, totk);
  }

  // 4. flash attention
  attn_kernel<<<dim3(S_LEN / QBLK, BATCH * NH), dim3(256), 0, stream>>>(qb, kb, vb, ab);

  // 5. output projection -> f32 d_out
  gemm_bt<1><<<dim3(D_MODEL / GBN, M / GBM), dim3(256), 0, stream>>>(ab, wob, out, nullptr, M, D_MODEL, D_MODEL);
}

// Round 4
// 495.782 us; speedup vs baseline: 1.4715x; 1.4715x over previous
//
#include <hip/hip_runtime.h>
#include <cstdint>
#include <cstddef>

#define S_LEN 2048
#define D_MODEL 2048
#define NH 32
#define NKV 8
#define HD_ 64
#define BATCH 2
#define KVD 512
#define MTOT 4096

typedef float f32x4 __attribute__((ext_vector_type(4)));
typedef short s16x8 __attribute__((ext_vector_type(8)));
typedef unsigned int u32;
typedef unsigned int u32x4 __attribute__((ext_vector_type(4)));

__device__ __forceinline__ unsigned short f2bf(float f) {
  unsigned int u = __builtin_bit_cast(unsigned int, f);
  u = (u + 0x7fffu + ((u >> 16) & 1u)) >> 16;
  return (unsigned short)u;
}
__device__ __forceinline__ float bf2f(unsigned short h) {
  return __builtin_bit_cast(float, ((unsigned int)h) << 16);
}

// async global->LDS, 16B per lane; LDS dest = wave-uniform base + lane*16 (linear only)
__device__ __forceinline__ void gl_lds16(const void* g, void* l) {
  __builtin_amdgcn_global_load_lds((const __attribute__((address_space(1))) u32*)g,
                                   (__attribute__((address_space(3))) u32*)l, 16, 0, 0);
}

// ---------------- f32 -> bf16 convert (vectorized x4) ----------------
__global__ void cvt_kernel(const float* __restrict__ in, unsigned short* __restrict__ out, int n4) {
  int i = blockIdx.x * blockDim.x + threadIdx.x;
  if (i >= n4) return;
  float4 v = reinterpret_cast<const float4*>(in)[i];
  ushort4 o;
  o.x = f2bf(v.x); o.y = f2bf(v.y); o.z = f2bf(v.z); o.w = f2bf(v.w);
  reinterpret_cast<ushort4*>(out)[i] = o;
}

// ---------------- RoPE in-place on bf16 buffer [B*S][nheads*64], optional scale ----------------
__global__ void rope_kernel(unsigned short* __restrict__ buf, const float* __restrict__ cosb,
                            const float* __restrict__ sinb, int nheads, int total, float scale) {
  int i = blockIdx.x * blockDim.x + threadIdx.x;
  if (i >= total) return;
  int pair = i & 31;
  int rest = i >> 5;
  int s = (rest / nheads) % S_LEN;
  float c = cosb[s * 32 + pair], sn = sinb[s * 32 + pair];
  size_t base = (size_t)rest * HD_ + (size_t)pair * 2;
  float r  = bf2f(buf[base]);
  float im = bf2f(buf[base + 1]);
  buf[base]     = f2bf((r * c - im * sn) * scale);
  buf[base + 1] = f2bf((r * sn + im * c) * scale);
}

// ---------------- GEMM: C[m][n] = sum_k A[m][k] * W[n][k], bf16 in, f32 acc ----------------
// Exact m97 replica: 128x128 tile, BK=32, global_load_lds w16, LINEAR LDS (64B rows, no swizzle).
// MODE 0: bf16 row-major out; 1: f32 row-major out; 2: bf16 transposed out (Vt).
template<int MODE>
__global__ __launch_bounds__(256) void gemm_bt(const unsigned short* __restrict__ A,
                                               const unsigned short* __restrict__ W,
                                               float* __restrict__ Cf,
                                               unsigned short* __restrict__ Cb,
                                               int M, int N, int K) {
  __shared__ alignas(16) short As[128 * 32];
  __shared__ alignas(16) short Bs[128 * 32];
  int tid = threadIdx.x;
  int lane = tid & 63, wid = tid >> 6;
  int m0 = blockIdx.y * 128;
  int n0 = blockIdx.x * 128;
  int wm = (wid >> 1) * 64, wn = (wid & 1) * 64;
  int lrow = lane & 15, lkk = lane >> 4;
  int srow = lane >> 2;          // 16 rows per 1KB chunk
  int scb  = (lane & 3) * 16;    // byte col within 64B row
  f32x4 acc[4][4] = {};

  for (int k0 = 0; k0 < K; k0 += 32) {
    __syncthreads();
#pragma unroll
    for (int i = 0; i < 2; ++i) {
      int c = wid * 2 + i;
      int row = c * 16 + srow;
      const char* ga = (const char*)A + ((size_t)(m0 + row) * K + k0) * 2 + scb;
      gl_lds16(ga, (char*)As + c * 1024);
      const char* gw = (const char*)W + ((size_t)(n0 + row) * K + k0) * 2 + scb;
      gl_lds16(gw, (char*)Bs + c * 1024);
    }
    __syncthreads();
    s16x8 af[4], bfr[4];
#pragma unroll
    for (int mi = 0; mi < 4; ++mi) {
      int row = wm + mi * 16 + lrow;
      af[mi] = *reinterpret_cast<const s16x8*>((const char*)As + row * 64 + lkk * 16);
    }
#pragma unroll
    for (int ni = 0; ni < 4; ++ni) {
      int row = wn + ni * 16 + lrow;
      bfr[ni] = *reinterpret_cast<const s16x8*>((const char*)Bs + row * 64 + lkk * 16);
    }
#pragma unroll
    for (int mi = 0; mi < 4; ++mi)
#pragma unroll
      for (int ni = 0; ni < 4; ++ni)
        acc[mi][ni] = __builtin_amdgcn_mfma_f32_16x16x32_bf16(af[mi], bfr[ni], acc[mi][ni], 0, 0, 0);
  }

#pragma unroll
  for (int mi = 0; mi < 4; ++mi)
#pragma unroll
    for (int ni = 0; ni < 4; ++ni) {
      if (MODE == 2) {
        int col = n0 + wn + ni * 16 + lrow;
        int mrow = m0 + wm + mi * 16 + lkk * 4;
        ushort4 o;
        o.x = f2bf(acc[mi][ni][0]); o.y = f2bf(acc[mi][ni][1]);
        o.z = f2bf(acc[mi][ni][2]); o.w = f2bf(acc[mi][ni][3]);
        *reinterpret_cast<ushort4*>(Cb + (size_t)col * M + mrow) = o;
      } else {
#pragma unroll
        for (int r = 0; r < 4; ++r) {
          int row = m0 + wm + mi * 16 + lkk * 4 + r;
          int col = n0 + wn + ni * 16 + lrow;
          if (MODE == 1) Cf[(size_t)row * N + col] = acc[mi][ni][r];
          else           Cb[(size_t)row * N + col] = f2bf(acc[mi][ni][r]);
        }
      }
    }
}

// ---------------- Flash attention (causal, GQA rep=4), swapped QK^T ----------------
// grid (S/64, B*NH); 256 threads = 4 waves, each wave owns 16 q rows. KV tile = 64.
// Reg-staged K/V with swizzled ds_write + identical-XOR read (round-0-proven pattern).
// T14: issue tile t+1's global loads before tile t's compute.
__global__ __launch_bounds__(256) void attn_kernel(const unsigned short* __restrict__ Q,
                                                   const unsigned short* __restrict__ Kb,
                                                   const unsigned short* __restrict__ Vt,
                                                   unsigned short* __restrict__ O) {
  __shared__ alignas(16) short Ks[64 * 64];   // [kv][d], 128B rows, XOR (row&7)<<4
  __shared__ alignas(16) short Vs[64 * 64];   // [d][kv] (from global Vt), same swizzle

  int tid = threadIdx.x, lane = tid & 63, wid = tid >> 6;
  int qi = lane & 15, lk = lane >> 4;
  int bh = blockIdx.y;
  int b = bh / NH, h = bh % NH, kvh = h >> 2;
  size_t bS = (size_t)b * S_LEN;
  int q0 = blockIdx.x * 64;
  int nt = blockIdx.x + 1;

  // Q frags (B-operand): col = qi, k = d contiguous. Q pre-scaled by 0.125 at RoPE.
  const unsigned short* qptr = Q + (bS + q0 + wid * 16 + qi) * D_MODEL + h * HD_;
  s16x8 qf0 = *reinterpret_cast<const s16x8*>(qptr + lk * 8);
  s16x8 qf1 = *reinterpret_cast<const s16x8*>(qptr + 32 + lk * 8);

  int srow = tid >> 3;           // 0..31 (two passes: +0, +32)
  int scb  = (tid & 7) * 16;     // byte col within 128B row

  f32x4 o_acc[4] = {};
  float m_run = -3.0e38f, l_run = 0.f;

  s16x8 kr0, kr1, vr0, vr1;
  auto GLOAD = [&](int t) {
    int kv0 = t * 64;
    kr0 = *reinterpret_cast<const s16x8*>((const char*)Kb + ((bS + kv0 + srow) * KVD + kvh * HD_) * 2 + scb);
    kr1 = *reinterpret_cast<const s16x8*>((const char*)Kb + ((bS + kv0 + srow + 32) * KVD + kvh * HD_) * 2 + scb);
    vr0 = *reinterpret_cast<const s16x8*>((const char*)Vt + ((size_t)(kvh * 64 + srow) * MTOT + bS + kv0) * 2 + scb);
    vr1 = *reinterpret_cast<const s16x8*>((const char*)Vt + ((size_t)(kvh * 64 + srow + 32) * MTOT + bS + kv0) * 2 + scb);
  };
  auto SWRITE = [&]() {
    int sw0 = (srow & 7) << 4;
    *reinterpret_cast<s16x8*>((char*)Ks + srow * 128 + (scb ^ sw0)) = kr0;
    *reinterpret_cast<s16x8*>((char*)Ks + (srow + 32) * 128 + (scb ^ sw0)) = kr1;
    *reinterpret_cast<s16x8*>((char*)Vs + srow * 128 + (scb ^ sw0)) = vr0;
    *reinterpret_cast<s16x8*>((char*)Vs + (srow + 32) * 128 + (scb ^ sw0)) = vr1;
  };

  GLOAD(0);
  SWRITE();
  __syncthreads();

  for (int t = 0; t < nt; ++t) {
    if (t + 1 < nt) GLOAD(t + 1);   // issue early; latency hides under MFMAs

    // S^T tiles: st[mt][r] = S^T[kv = mt*16 + 4*lk + r][q = qi]
    f32x4 st[4];
#pragma unroll
    for (int mt = 0; mt < 4; ++mt) {
      int row = mt * 16 + qi;
      int sw = (row & 7) << 4;
      s16x8 ka0 = *reinterpret_cast<const s16x8*>((const char*)Ks + row * 128 + ((lk * 16) ^ sw));
      s16x8 ka1 = *reinterpret_cast<const s16x8*>((const char*)Ks + row * 128 + ((64 + lk * 16) ^ sw));
      f32x4 a = {};
      a = __builtin_amdgcn_mfma_f32_16x16x32_bf16(ka0, qf0, a, 0, 0, 0);
      a = __builtin_amdgcn_mfma_f32_16x16x32_bf16(ka1, qf1, a, 0, 0, 0);
      st[mt] = a;
    }

    if (t == nt - 1) {  // diagonal tile: mask kv_local > q_local
      int ql = wid * 16 + qi;
#pragma unroll
      for (int mt = 0; mt < 4; ++mt)
#pragma unroll
        for (int r = 0; r < 4; ++r) {
          int kvl = mt * 16 + 4 * lk + r;
          if (kvl > ql) st[mt][r] = -3.0e38f;
        }
    }

    // online softmax for q-col = qi (4 lanes {qi+16*lk} share a q-row)
    float pmax = st[0][0];
#pragma unroll
    for (int mt = 0; mt < 4; ++mt)
#pragma unroll
      for (int r = 0; r < 4; ++r) pmax = fmaxf(pmax, st[mt][r]);
    pmax = fmaxf(pmax, __shfl_xor(pmax, 16, 64));
    pmax = fmaxf(pmax, __shfl_xor(pmax, 32, 64));
    float mnew = fmaxf(m_run, pmax);
    float alpha = __expf(m_run - mnew);
    m_run = mnew;
    float psum = 0.f;
#pragma unroll
    for (int mt = 0; mt < 4; ++mt)
#pragma unroll
      for (int r = 0; r < 4; ++r) {
        float p = __expf(st[mt][r] - mnew);
        st[mt][r] = p;
        psum += p;
      }
    psum += __shfl_xor(psum, 16, 64);
    psum += __shfl_xor(psum, 32, 64);
    l_run = l_run * alpha + psum;

    // pack P^T pairs to bf16 (RNE, explicit bit ops — no v_perm)
    u32 pk[4][2];
#pragma unroll
    for (int mt = 0; mt < 4; ++mt)
#pragma unroll
      for (int w = 0; w < 2; ++w)
        pk[mt][w] = (u32)f2bf(st[mt][2 * w]) | ((u32)f2bf(st[mt][2 * w + 1]) << 16);

    // rescale O by alpha (per O-row q = 4*lk + r)
    float ar[4];
#pragma unroll
    for (int r = 0; r < 4; ++r) ar[r] = __shfl(alpha, 4 * lk + r, 64);
#pragma unroll
    for (int n = 0; n < 4; ++n)
#pragma unroll
      for (int r = 0; r < 4; ++r) o_acc[n][r] *= ar[r];

    // redistribute P^T -> PV A-frags: pa[ks] word u = P[q=qi][kv=32ks+8lk+2u{,+1}]
    int s0 = qi + 32 * (lk & 1);
    int s2 = s0 + 16;
    bool hiw = lk >= 2;
    s16x8 pa[2];
#pragma unroll
    for (int ks = 0; ks < 2; ++ks) {
      u32 a0 = (u32)__shfl((int)pk[2 * ks][0], s0, 64), b0 = (u32)__shfl((int)pk[2 * ks + 1][0], s0, 64);
      u32 a1 = (u32)__shfl((int)pk[2 * ks][1], s0, 64), b1 = (u32)__shfl((int)pk[2 * ks + 1][1], s0, 64);
      u32 a2 = (u32)__shfl((int)pk[2 * ks][0], s2, 64), b2 = (u32)__shfl((int)pk[2 * ks + 1][0], s2, 64);
      u32 a3 = (u32)__shfl((int)pk[2 * ks][1], s2, 64), b3 = (u32)__shfl((int)pk[2 * ks + 1][1], s2, 64);
      u32x4 wv_;
      wv_[0] = hiw ? b0 : a0; wv_[1] = hiw ? b1 : a1;
      wv_[2] = hiw ? b2 : a2; wv_[3] = hiw ? b3 : a3;
      pa[ks] = __builtin_bit_cast(s16x8, wv_);
    }

    // PV: O[q][d] += P * V ; B-frag from Vs rows (d), contiguous kv
#pragma unroll
    for (int n = 0; n < 4; ++n) {
      int vr = n * 16 + qi;
      int sw = (vr & 7) << 4;
      s16x8 vb0 = *reinterpret_cast<const s16x8*>((const char*)Vs + vr * 128 + ((lk * 16) ^ sw));
      s16x8 vb1 = *reinterpret_cast<const s16x8*>((const char*)Vs + vr * 128 + ((64 + lk * 16) ^ sw));
      o_acc[n] = __builtin_amdgcn_mfma_f32_16x16x32_bf16(pa[0], vb0, o_acc[n], 0, 0, 0);
      o_acc[n] = __builtin_amdgcn_mfma_f32_16x16x32_bf16(pa[1], vb1, o_acc[n], 0, 0, 0);
    }

    __syncthreads();                 // all reads of this tile done
    if (t + 1 < nt) SWRITE();        // stage next tile
    __syncthreads();                 // writes visible
  }

  // epilogue: O C-layout row q=4lk+r, col d=16n+qi
  float linv[4];
#pragma unroll
  for (int r = 0; r < 4; ++r) linv[r] = 1.0f / __shfl(l_run, 4 * lk + r, 64);
#pragma unroll
  for (int n = 0; n < 4; ++n)
#pragma unroll
    for (int r = 0; r < 4; ++r) {
      size_t row = bS + q0 + wid * 16 + 4 * lk + r;
      int col = h * HD_ + n * 16 + qi;
      O[row * D_MODEL + col] = f2bf(o_acc[n][r] * linv[r]);
    }
}

// ---------------- launch ----------------
extern "C" void kernel_launch(void* const* d_in, const int* in_sizes, int n_in,
                              void* d_out, int out_size, void* d_ws, size_t ws_size,
                              hipStream_t stream) {
  const float* x  = (const float*)d_in[0];
  const float* fc = (const float*)d_in[1];
  const float* fs = (const float*)d_in[2];
  const float* wq = (const float*)d_in[3];
  const float* wk = (const float*)d_in[4];
  const float* wv = (const float*)d_in[5];
  const float* wo = (const float*)d_in[6];
  float* out = (float*)d_out;

  const size_t nx  = (size_t)BATCH * S_LEN * D_MODEL;
  const size_t nw  = (size_t)D_MODEL * D_MODEL;
  const size_t nwk = (size_t)KVD * D_MODEL;
  const size_t nkv = (size_t)BATCH * S_LEN * KVD;

  char* ws = (char*)d_ws;
  unsigned short* xb  = (unsigned short*)ws;  ws += nx  * 2;
  unsigned short* wqb = (unsigned short*)ws;  ws += nw  * 2;
  unsigned short* wkb = (unsigned short*)ws;  ws += nwk * 2;
  unsigned short* wvb = (unsigned short*)ws;  ws += nwk * 2;
  unsigned short* wob = (unsigned short*)ws;  ws += nw  * 2;
  unsigned short* qb  = (unsigned short*)ws;  ws += nx  * 2;
  unsigned short* kb  = (unsigned short*)ws;  ws += nkv * 2;
  unsigned short* vtb = (unsigned short*)ws;  ws += nkv * 2;   // V^T [KVD][MTOT]
  unsigned short* ab  = (unsigned short*)ws;  ws += nx  * 2;

  cvt_kernel<<<dim3((nx / 4 + 255) / 256), dim3(256), 0, stream>>>(x, xb, nx / 4);
  cvt_kernel<<<dim3((nw / 4 + 255) / 256), dim3(256), 0, stream>>>(wq, wqb, nw / 4);
  cvt_kernel<<<dim3((nwk / 4 + 255) / 256), dim3(256), 0, stream>>>(wk, wkb, nwk / 4);
  cvt_kernel<<<dim3((nwk / 4 + 255) / 256), dim3(256), 0, stream>>>(wv, wvb, nwk / 4);
  cvt_kernel<<<dim3((nw / 4 + 255) / 256), dim3(256), 0, stream>>>(wo, wob, nw / 4);

  const int M = BATCH * S_LEN;  // 4096
  gemm_bt<0><<<dim3(D_MODEL / 128, M / 128), dim3(256), 0, stream>>>(xb, wqb, nullptr, qb, M, D_MODEL, D_MODEL);
  gemm_bt<0><<<dim3(KVD / 128, M / 128), dim3(256), 0, stream>>>(xb, wkb, nullptr, kb, M, KVD, D_MODEL);
  gemm_bt<2><<<dim3(KVD / 128, M / 128), dim3(256), 0, stream>>>(xb, wvb, nullptr, vtb, M, KVD, D_MODEL);

  {
    int totq = BATCH * S_LEN * NH * 32;
    int totk = BATCH * S_LEN * NKV * 32;
    rope_kernel<<<dim3((totq + 255) / 256), dim3(256), 0, stream>>>(qb, fc, fs, NH, totq, 0.125f);
    rope_kernel<<<dim3((totk + 255) / 256), dim3(256), 0, stream>>>(kb, fc, fs, NKV, totk, 1.0f);
  }

  attn_kernel<<<dim3(S_LEN / 64, BATCH * NH), dim3(256), 0, stream>>>(qb, kb, vtb, ab);

  gemm_bt<1><<<dim3(D_MODEL / 128, M / 128), dim3(256), 0, stream>>>(ab, wob, out, nullptr, M, D_MODEL, D_MODEL);
}

// Round 6
// 392.358 us; speedup vs baseline: 1.8594x; 1.2636x over previous
//
#include <hip/hip_runtime.h>
#include <cstdint>
#include <cstddef>

#define S_LEN 2048
#define D_MODEL 2048
#define NH 32
#define NKV 8
#define HD_ 64
#define BATCH 2
#define KVD 512
#define MTOT 4096

typedef float f32x4 __attribute__((ext_vector_type(4)));
typedef short s16x8 __attribute__((ext_vector_type(8)));
typedef unsigned int u32;
typedef unsigned int u32x4 __attribute__((ext_vector_type(4)));

__device__ __forceinline__ unsigned short f2bf(float f) {
  unsigned int u = __builtin_bit_cast(unsigned int, f);
  u = (u + 0x7fffu + ((u >> 16) & 1u)) >> 16;
  return (unsigned short)u;
}
__device__ __forceinline__ float bf2f(unsigned short h) {
  return __builtin_bit_cast(float, ((unsigned int)h) << 16);
}
__device__ __forceinline__ float fexp2(float x) {
#if __has_builtin(__builtin_amdgcn_exp2f)
  return __builtin_amdgcn_exp2f(x);
#else
  return exp2f(x);
#endif
}

// async global->LDS, 16B per lane; LDS dest = wave-uniform base + lane*16 (linear only)
__device__ __forceinline__ void gl_lds16(const void* g, void* l) {
  __builtin_amdgcn_global_load_lds((const __attribute__((address_space(1))) u32*)g,
                                   (__attribute__((address_space(3))) u32*)l, 16, 0, 0);
}

// ---------------- f32 -> bf16 convert (vectorized x4) ----------------
__global__ void cvt_kernel(const float* __restrict__ in, unsigned short* __restrict__ out, int n4) {
  int i = blockIdx.x * blockDim.x + threadIdx.x;
  if (i >= n4) return;
  float4 v = reinterpret_cast<const float4*>(in)[i];
  ushort4 o;
  o.x = f2bf(v.x); o.y = f2bf(v.y); o.z = f2bf(v.z); o.w = f2bf(v.w);
  reinterpret_cast<ushort4*>(out)[i] = o;
}

// ---------------- fused 4-tensor f32 -> bf16 convert ----------------
__global__ void cvt4_kernel(const float* __restrict__ a, const float* __restrict__ b,
                            const float* __restrict__ c, const float* __restrict__ d,
                            unsigned short* __restrict__ oa, unsigned short* __restrict__ ob,
                            unsigned short* __restrict__ oc, unsigned short* __restrict__ od,
                            int na4, int nb4, int nc4, int nd4) {
  int j = blockIdx.x * blockDim.x + threadIdx.x;
  const float* src; unsigned short* dst;
  if (j < na4) { src = a; dst = oa; }
  else {
    j -= na4;
    if (j < nb4) { src = b; dst = ob; }
    else {
      j -= nb4;
      if (j < nc4) { src = c; dst = oc; }
      else {
        j -= nc4;
        if (j >= nd4) return;
        src = d; dst = od;
      }
    }
  }
  float4 v = reinterpret_cast<const float4*>(src)[j];
  ushort4 o;
  o.x = f2bf(v.x); o.y = f2bf(v.y); o.z = f2bf(v.z); o.w = f2bf(v.w);
  reinterpret_cast<ushort4*>(dst)[j] = o;
}

// ---------------- fused RoPE (q then k), in-place, optional scale on q ----------------
__global__ void rope2_kernel(unsigned short* __restrict__ qb, unsigned short* __restrict__ kb,
                             const float* __restrict__ cosb, const float* __restrict__ sinb,
                             int totq, int totk, float qscale) {
  int i = blockIdx.x * blockDim.x + threadIdx.x;
  unsigned short* buf; int nheads; float scale;
  if (i < totq) { buf = qb; nheads = NH; scale = qscale; }
  else {
    i -= totq;
    if (i >= totk) return;
    buf = kb; nheads = NKV; scale = 1.0f;
  }
  int pair = i & 31;
  int rest = i >> 5;
  int s = (rest / nheads) % S_LEN;
  float c = cosb[s * 32 + pair], sn = sinb[s * 32 + pair];
  size_t base = (size_t)rest * HD_ + (size_t)pair * 2;
  float r  = bf2f(buf[base]);
  float im = bf2f(buf[base + 1]);
  buf[base]     = f2bf((r * c - im * sn) * scale);
  buf[base + 1] = f2bf((r * sn + im * c) * scale);
}

// ---------------- GEMM: C[m][n] = sum_k A[m][k] * W[n][k], bf16 in, f32 acc ----------------
// m97 replica: 128x128 tile, BK=32, global_load_lds w16, LINEAR LDS (64B rows, no swizzle).
// MODE 0: bf16 row-major out; 1: f32 row-major out.
template<int MODE>
__global__ __launch_bounds__(256) void gemm_bt(const unsigned short* __restrict__ A,
                                               const unsigned short* __restrict__ W,
                                               float* __restrict__ Cf,
                                               unsigned short* __restrict__ Cb,
                                               int M, int N, int K) {
  __shared__ alignas(16) short As[128 * 32];
  __shared__ alignas(16) short Bs[128 * 32];
  int tid = threadIdx.x;
  int lane = tid & 63, wid = tid >> 6;
  int m0 = blockIdx.y * 128;
  int n0 = blockIdx.x * 128;
  int wm = (wid >> 1) * 64, wn = (wid & 1) * 64;
  int lrow = lane & 15, lkk = lane >> 4;
  int srow = lane >> 2;
  int scb  = (lane & 3) * 16;
  f32x4 acc[4][4] = {};

  for (int k0 = 0; k0 < K; k0 += 32) {
    __syncthreads();
#pragma unroll
    for (int i = 0; i < 2; ++i) {
      int c = wid * 2 + i;
      int row = c * 16 + srow;
      const char* ga = (const char*)A + ((size_t)(m0 + row) * K + k0) * 2 + scb;
      gl_lds16(ga, (char*)As + c * 1024);
      const char* gw = (const char*)W + ((size_t)(n0 + row) * K + k0) * 2 + scb;
      gl_lds16(gw, (char*)Bs + c * 1024);
    }
    __syncthreads();
    s16x8 af[4], bfr[4];
#pragma unroll
    for (int mi = 0; mi < 4; ++mi) {
      int row = wm + mi * 16 + lrow;
      af[mi] = *reinterpret_cast<const s16x8*>((const char*)As + row * 64 + lkk * 16);
    }
#pragma unroll
    for (int ni = 0; ni < 4; ++ni) {
      int row = wn + ni * 16 + lrow;
      bfr[ni] = *reinterpret_cast<const s16x8*>((const char*)Bs + row * 64 + lkk * 16);
    }
#pragma unroll
    for (int mi = 0; mi < 4; ++mi)
#pragma unroll
      for (int ni = 0; ni < 4; ++ni)
        acc[mi][ni] = __builtin_amdgcn_mfma_f32_16x16x32_bf16(af[mi], bfr[ni], acc[mi][ni], 0, 0, 0);
  }

#pragma unroll
  for (int mi = 0; mi < 4; ++mi)
#pragma unroll
    for (int ni = 0; ni < 4; ++ni)
#pragma unroll
      for (int r = 0; r < 4; ++r) {
        int row = m0 + wm + mi * 16 + lkk * 4 + r;
        int col = n0 + wn + ni * 16 + lrow;
        if (MODE == 1) Cf[(size_t)row * N + col] = acc[mi][ni][r];
        else           Cb[(size_t)row * N + col] = f2bf(acc[mi][ni][r]);
      }
}

// ---------------- fused K+V projection: one dispatch, 256 blocks ----------------
// blockIdx.x < 4: K-proj -> Ck row-major [M][KVD]; else V-proj -> Cvt transposed [KVD][M].
__global__ __launch_bounds__(256) void gemm_kv(const unsigned short* __restrict__ A,
                                               const unsigned short* __restrict__ Wk,
                                               const unsigned short* __restrict__ Wv,
                                               unsigned short* __restrict__ Ck,
                                               unsigned short* __restrict__ Cvt,
                                               int M, int K) {
  __shared__ alignas(16) short As[128 * 32];
  __shared__ alignas(16) short Bs[128 * 32];
  int tid = threadIdx.x;
  int lane = tid & 63, wid = tid >> 6;
  bool isV = blockIdx.x >= 4;
  const unsigned short* W = isV ? Wv : Wk;
  int n0 = (isV ? (int)blockIdx.x - 4 : (int)blockIdx.x) * 128;
  int m0 = blockIdx.y * 128;
  int wm = (wid >> 1) * 64, wn = (wid & 1) * 64;
  int lrow = lane & 15, lkk = lane >> 4;
  int srow = lane >> 2;
  int scb  = (lane & 3) * 16;
  f32x4 acc[4][4] = {};

  for (int k0 = 0; k0 < K; k0 += 32) {
    __syncthreads();
#pragma unroll
    for (int i = 0; i < 2; ++i) {
      int c = wid * 2 + i;
      int row = c * 16 + srow;
      const char* ga = (const char*)A + ((size_t)(m0 + row) * K + k0) * 2 + scb;
      gl_lds16(ga, (char*)As + c * 1024);
      const char* gw = (const char*)W + ((size_t)(n0 + row) * K + k0) * 2 + scb;
      gl_lds16(gw, (char*)Bs + c * 1024);
    }
    __syncthreads();
    s16x8 af[4], bfr[4];
#pragma unroll
    for (int mi = 0; mi < 4; ++mi) {
      int row = wm + mi * 16 + lrow;
      af[mi] = *reinterpret_cast<const s16x8*>((const char*)As + row * 64 + lkk * 16);
    }
#pragma unroll
    for (int ni = 0; ni < 4; ++ni) {
      int row = wn + ni * 16 + lrow;
      bfr[ni] = *reinterpret_cast<const s16x8*>((const char*)Bs + row * 64 + lkk * 16);
    }
#pragma unroll
    for (int mi = 0; mi < 4; ++mi)
#pragma unroll
      for (int ni = 0; ni < 4; ++ni)
        acc[mi][ni] = __builtin_amdgcn_mfma_f32_16x16x32_bf16(af[mi], bfr[ni], acc[mi][ni], 0, 0, 0);
  }

  if (!isV) {
#pragma unroll
    for (int mi = 0; mi < 4; ++mi)
#pragma unroll
      for (int ni = 0; ni < 4; ++ni)
#pragma unroll
        for (int r = 0; r < 4; ++r) {
          int row = m0 + wm + mi * 16 + lkk * 4 + r;
          int col = n0 + wn + ni * 16 + lrow;
          Ck[(size_t)row * KVD + col] = f2bf(acc[mi][ni][r]);
        }
  } else {
#pragma unroll
    for (int mi = 0; mi < 4; ++mi)
#pragma unroll
      for (int ni = 0; ni < 4; ++ni) {
        int col = n0 + wn + ni * 16 + lrow;
        int mrow = m0 + wm + mi * 16 + lkk * 4;
        ushort4 o;
        o.x = f2bf(acc[mi][ni][0]); o.y = f2bf(acc[mi][ni][1]);
        o.z = f2bf(acc[mi][ni][2]); o.w = f2bf(acc[mi][ni][3]);
        *reinterpret_cast<ushort4*>(Cvt + (size_t)col * M + mrow) = o;
      }
  }
}

// ---------------- Flash attention (causal, GQA rep=4), swapped QK^T ----------------
// Balanced pairing: block handles q-tiles x and 31-x (33 KV-tiles each). grid (16, B*NH).
// Double-buffered LDS, 1 barrier/tile. exp2-domain softmax (Q pre-scaled by 0.125*log2e).
__global__ __launch_bounds__(256) void attn_kernel(const unsigned short* __restrict__ Q,
                                                   const unsigned short* __restrict__ Kb,
                                                   const unsigned short* __restrict__ Vt,
                                                   unsigned short* __restrict__ O) {
  __shared__ alignas(16) short Ks[2][64 * 64];   // [kv][d], 128B rows, XOR (row&7)<<4
  __shared__ alignas(16) short Vs[2][64 * 64];   // [d][kv] (from global Vt), same swizzle

  int tid = threadIdx.x, lane = tid & 63, wid = tid >> 6;
  int qi = lane & 15, lk = lane >> 4;
  int bh = blockIdx.y;
  int b = bh / NH, h = bh % NH, kvh = h >> 2;
  size_t bS = (size_t)b * S_LEN;
  int srow = tid >> 3;           // 0..31 (two passes: +0, +32)
  int scb  = (tid & 7) * 16;     // byte col within 128B row
  int sw0  = (srow & 7) << 4;

  const char* kbG = (const char*)Kb + (bS * KVD + (size_t)kvh * HD_) * 2;
  const char* vtG = (const char*)Vt + ((size_t)(kvh * 64) * MTOT + bS) * 2;

  s16x8 kr0, kr1, vr0, vr1;
  auto GLOAD = [&](int kv0) {
    kr0 = *reinterpret_cast<const s16x8*>(kbG + (size_t)(kv0 + srow) * (KVD * 2) + scb);
    kr1 = *reinterpret_cast<const s16x8*>(kbG + (size_t)(kv0 + srow + 32) * (KVD * 2) + scb);
    vr0 = *reinterpret_cast<const s16x8*>(vtG + (size_t)srow * (MTOT * 2) + kv0 * 2 + scb);
    vr1 = *reinterpret_cast<const s16x8*>(vtG + (size_t)(srow + 32) * (MTOT * 2) + kv0 * 2 + scb);
  };
  auto SWRITE = [&](int bf) {
    *reinterpret_cast<s16x8*>((char*)Ks[bf] + srow * 128 + (scb ^ sw0)) = kr0;
    *reinterpret_cast<s16x8*>((char*)Ks[bf] + (srow + 32) * 128 + (scb ^ sw0)) = kr1;
    *reinterpret_cast<s16x8*>((char*)Vs[bf] + srow * 128 + (scb ^ sw0)) = vr0;
    *reinterpret_cast<s16x8*>((char*)Vs[bf] + (srow + 32) * 128 + (scb ^ sw0)) = vr1;
  };

#pragma unroll 1
  for (int job = 0; job < 2; ++job) {
    int qtile = (job == 0) ? (int)blockIdx.x : 31 - (int)blockIdx.x;
    int q0 = qtile * 64;
    int nt = qtile + 1;

    // Q frags (B-operand): col = qi, k = d contiguous. Q pre-scaled by 0.125*log2e at RoPE.
    const unsigned short* qptr = Q + (bS + q0 + wid * 16 + qi) * D_MODEL + h * HD_;
    s16x8 qf0 = *reinterpret_cast<const s16x8*>(qptr + lk * 8);
    s16x8 qf1 = *reinterpret_cast<const s16x8*>(qptr + 32 + lk * 8);

    f32x4 o_acc[4] = {};
    float m_run = -3.0e38f, l_run = 0.f;

    GLOAD(0);
    SWRITE(0);
    __syncthreads();
    int cur = 0;

    for (int t = 0; t < nt; ++t) {
      if (t + 1 < nt) GLOAD((t + 1) * 64);   // issue early; latency hides under compute

      const char* kbase = (const char*)Ks[cur];
      const char* vbase = (const char*)Vs[cur];

      // S^T tiles: st[mt][r] = S^T[kv = mt*16 + 4*lk + r][q = qi]  (log2 domain)
      f32x4 st[4];
      __builtin_amdgcn_s_setprio(1);
#pragma unroll
      for (int mt = 0; mt < 4; ++mt) {
        int row = mt * 16 + qi;
        int sw = (row & 7) << 4;
        s16x8 ka0 = *reinterpret_cast<const s16x8*>(kbase + row * 128 + ((lk * 16) ^ sw));
        s16x8 ka1 = *reinterpret_cast<const s16x8*>(kbase + row * 128 + ((64 + lk * 16) ^ sw));
        f32x4 a = {};
        a = __builtin_amdgcn_mfma_f32_16x16x32_bf16(ka0, qf0, a, 0, 0, 0);
        a = __builtin_amdgcn_mfma_f32_16x16x32_bf16(ka1, qf1, a, 0, 0, 0);
        st[mt] = a;
      }
      __builtin_amdgcn_s_setprio(0);

      if (t == nt - 1) {  // diagonal tile: mask kv_local > q_local
        int ql = wid * 16 + qi;
#pragma unroll
        for (int mt = 0; mt < 4; ++mt)
#pragma unroll
          for (int r = 0; r < 4; ++r) {
            int kvl = mt * 16 + 4 * lk + r;
            if (kvl > ql) st[mt][r] = -3.0e38f;
          }
      }

      // online softmax for q-col = qi (4 lanes {qi+16*lk} share a q-row), exp2 domain
      float pmax = st[0][0];
#pragma unroll
      for (int mt = 0; mt < 4; ++mt)
#pragma unroll
        for (int r = 0; r < 4; ++r) pmax = fmaxf(pmax, st[mt][r]);
      pmax = fmaxf(pmax, __shfl_xor(pmax, 16, 64));
      pmax = fmaxf(pmax, __shfl_xor(pmax, 32, 64));
      float mnew = fmaxf(m_run, pmax);
      float alpha = fexp2(m_run - mnew);
      m_run = mnew;
      float psum = 0.f;
#pragma unroll
      for (int mt = 0; mt < 4; ++mt)
#pragma unroll
        for (int r = 0; r < 4; ++r) {
          float p = fexp2(st[mt][r] - mnew);
          st[mt][r] = p;
          psum += p;
        }
      psum += __shfl_xor(psum, 16, 64);
      psum += __shfl_xor(psum, 32, 64);
      l_run = l_run * alpha + psum;

      // pack P^T pairs to bf16 (RNE)
      u32 pk[4][2];
#pragma unroll
      for (int mt = 0; mt < 4; ++mt)
#pragma unroll
        for (int w = 0; w < 2; ++w)
          pk[mt][w] = (u32)f2bf(st[mt][2 * w]) | ((u32)f2bf(st[mt][2 * w + 1]) << 16);

      // rescale O by alpha (per O-row q = 4*lk + r)
      float ar[4];
#pragma unroll
      for (int r = 0; r < 4; ++r) ar[r] = __shfl(alpha, 4 * lk + r, 64);
#pragma unroll
      for (int n = 0; n < 4; ++n)
#pragma unroll
        for (int r = 0; r < 4; ++r) o_acc[n][r] *= ar[r];

      // redistribute P^T -> PV A-frags: pa[ks] word u = P[q=qi][kv=32ks+8lk+2u{,+1}]
      int s0 = qi + 32 * (lk & 1);
      int s2 = s0 + 16;
      bool hiw = lk >= 2;
      s16x8 pa[2];
#pragma unroll
      for (int ks = 0; ks < 2; ++ks) {
        u32 a0 = (u32)__shfl((int)pk[2 * ks][0], s0, 64), b0 = (u32)__shfl((int)pk[2 * ks + 1][0], s0, 64);
        u32 a1 = (u32)__shfl((int)pk[2 * ks][1], s0, 64), b1 = (u32)__shfl((int)pk[2 * ks + 1][1], s0, 64);
        u32 a2 = (u32)__shfl((int)pk[2 * ks][0], s2, 64), b2 = (u32)__shfl((int)pk[2 * ks + 1][0], s2, 64);
        u32 a3 = (u32)__shfl((int)pk[2 * ks][1], s2, 64), b3 = (u32)__shfl((int)pk[2 * ks + 1][1], s2, 64);
        u32x4 wv_;
        wv_[0] = hiw ? b0 : a0; wv_[1] = hiw ? b1 : a1;
        wv_[2] = hiw ? b2 : a2; wv_[3] = hiw ? b3 : a3;
        pa[ks] = __builtin_bit_cast(s16x8, wv_);
      }

      // PV: O[q][d] += P * V ; B-frag from Vs rows (d), contiguous kv
      __builtin_amdgcn_s_setprio(1);
#pragma unroll
      for (int n = 0; n < 4; ++n) {
        int vr = n * 16 + qi;
        int sw = (vr & 7) << 4;
        s16x8 vb0 = *reinterpret_cast<const s16x8*>(vbase + vr * 128 + ((lk * 16) ^ sw));
        s16x8 vb1 = *reinterpret_cast<const s16x8*>(vbase + vr * 128 + ((64 + lk * 16) ^ sw));
        o_acc[n] = __builtin_amdgcn_mfma_f32_16x16x32_bf16(pa[0], vb0, o_acc[n], 0, 0, 0);
        o_acc[n] = __builtin_amdgcn_mfma_f32_16x16x32_bf16(pa[1], vb1, o_acc[n], 0, 0, 0);
      }
      __builtin_amdgcn_s_setprio(0);

      if (t + 1 < nt) SWRITE(cur ^ 1);   // next tile into other buffer
      __syncthreads();
      cur ^= 1;
    }

    // epilogue: O C-layout row q=4lk+r, col d=16n+qi
    float linv[4];
#pragma unroll
    for (int r = 0; r < 4; ++r) linv[r] = 1.0f / __shfl(l_run, 4 * lk + r, 64);
#pragma unroll
    for (int n = 0; n < 4; ++n)
#pragma unroll
      for (int r = 0; r < 4; ++r) {
        size_t row = bS + q0 + wid * 16 + 4 * lk + r;
        int col = h * HD_ + n * 16 + qi;
        O[row * D_MODEL + col] = f2bf(o_acc[n][r] * linv[r]);
      }
  }
}

// ---------------- launch ----------------
extern "C" void kernel_launch(void* const* d_in, const int* in_sizes, int n_in,
                              void* d_out, int out_size, void* d_ws, size_t ws_size,
                              hipStream_t stream) {
  const float* x  = (const float*)d_in[0];
  const float* fc = (const float*)d_in[1];
  const float* fs = (const float*)d_in[2];
  const float* wq = (const float*)d_in[3];
  const float* wk = (const float*)d_in[4];
  const float* wv = (const float*)d_in[5];
  const float* wo = (const float*)d_in[6];
  float* out = (float*)d_out;

  const size_t nx  = (size_t)BATCH * S_LEN * D_MODEL;
  const size_t nw  = (size_t)D_MODEL * D_MODEL;
  const size_t nwk = (size_t)KVD * D_MODEL;
  const size_t nkv = (size_t)BATCH * S_LEN * KVD;

  char* ws = (char*)d_ws;
  unsigned short* xb  = (unsigned short*)ws;  ws += nx  * 2;
  unsigned short* wqb = (unsigned short*)ws;  ws += nw  * 2;
  unsigned short* wkb = (unsigned short*)ws;  ws += nwk * 2;
  unsigned short* wvb = (unsigned short*)ws;  ws += nwk * 2;
  unsigned short* wob = (unsigned short*)ws;  ws += nw  * 2;
  unsigned short* qb  = (unsigned short*)ws;  ws += nx  * 2;
  unsigned short* kb  = (unsigned short*)ws;  ws += nkv * 2;
  unsigned short* vtb = (unsigned short*)ws;  ws += nkv * 2;   // V^T [KVD][MTOT]
  unsigned short* ab  = (unsigned short*)ws;  ws += nx  * 2;

  cvt_kernel<<<dim3((nx / 4 + 255) / 256), dim3(256), 0, stream>>>(x, xb, nx / 4);
  {
    int na4 = nw / 4, nb4 = nwk / 4, nc4 = nwk / 4, nd4 = nw / 4;
    int tot = na4 + nb4 + nc4 + nd4;
    cvt4_kernel<<<dim3((tot + 255) / 256), dim3(256), 0, stream>>>(wq, wk, wv, wo, wqb, wkb, wvb, wob,
                                                                   na4, nb4, nc4, nd4);
  }

  const int M = BATCH * S_LEN;  // 4096
  gemm_bt<0><<<dim3(D_MODEL / 128, M / 128), dim3(256), 0, stream>>>(xb, wqb, nullptr, qb, M, D_MODEL, D_MODEL);
  gemm_kv<<<dim3(8, M / 128), dim3(256), 0, stream>>>(xb, wkb, wvb, kb, vtb, M, D_MODEL);

  {
    int totq = BATCH * S_LEN * NH * 32;
    int totk = BATCH * S_LEN * NKV * 32;
    // 0.125 * log2(e): QK^T lands directly in exp2 domain
    rope2_kernel<<<dim3((totq + totk + 255) / 256), dim3(256), 0, stream>>>(qb, kb, fc, fs, totq, totk,
                                                                            0.18033688011112042f);
  }

  attn_kernel<<<dim3(16, BATCH * NH), dim3(256), 0, stream>>>(qb, kb, vtb, ab);

  gemm_bt<1><<<dim3(D_MODEL / 128, M / 128), dim3(256), 0, stream>>>(ab, wob, out, nullptr, M, D_MODEL, D_MODEL);
}

// Round 7
// 336.280 us; speedup vs baseline: 2.1695x; 1.1668x over previous
//
#include <hip/hip_runtime.h>
#include <cstdint>
#include <cstddef>

#define S_LEN 2048
#define D_MODEL 2048
#define NH 32
#define NKV 8
#define HD_ 64
#define BATCH 2
#define KVD 512
#define MTOT 4096

typedef float f32x4 __attribute__((ext_vector_type(4)));
typedef short s16x8 __attribute__((ext_vector_type(8)));
typedef unsigned int u32;
typedef unsigned int u32x4 __attribute__((ext_vector_type(4)));

__device__ __forceinline__ unsigned short f2bf(float f) {
  unsigned int u = __builtin_bit_cast(unsigned int, f);
  u = (u + 0x7fffu + ((u >> 16) & 1u)) >> 16;
  return (unsigned short)u;
}
__device__ __forceinline__ float bf2f(unsigned short h) {
  return __builtin_bit_cast(float, ((unsigned int)h) << 16);
}
__device__ __forceinline__ float fexp2(float x) {
#if __has_builtin(__builtin_amdgcn_exp2f)
  return __builtin_amdgcn_exp2f(x);
#else
  return exp2f(x);
#endif
}

// async global->LDS, 16B per lane; LDS dest = wave-uniform base + lane*16 (linear only)
__device__ __forceinline__ void gl_lds16(const void* g, void* l) {
  __builtin_amdgcn_global_load_lds((const __attribute__((address_space(1))) u32*)g,
                                   (__attribute__((address_space(3))) u32*)l, 16, 0, 0);
}

// ---------------- f32 -> bf16 convert (vectorized x4) ----------------
__global__ void cvt_kernel(const float* __restrict__ in, unsigned short* __restrict__ out, int n4) {
  int i = blockIdx.x * blockDim.x + threadIdx.x;
  if (i >= n4) return;
  float4 v = reinterpret_cast<const float4*>(in)[i];
  ushort4 o;
  o.x = f2bf(v.x); o.y = f2bf(v.y); o.z = f2bf(v.z); o.w = f2bf(v.w);
  reinterpret_cast<ushort4*>(out)[i] = o;
}

// ---------------- fused 4-tensor f32 -> bf16 convert ----------------
__global__ void cvt4_kernel(const float* __restrict__ a, const float* __restrict__ b,
                            const float* __restrict__ c, const float* __restrict__ d,
                            unsigned short* __restrict__ oa, unsigned short* __restrict__ ob,
                            unsigned short* __restrict__ oc, unsigned short* __restrict__ od,
                            int na4, int nb4, int nc4, int nd4) {
  int j = blockIdx.x * blockDim.x + threadIdx.x;
  const float* src; unsigned short* dst;
  if (j < na4) { src = a; dst = oa; }
  else {
    j -= na4;
    if (j < nb4) { src = b; dst = ob; }
    else {
      j -= nb4;
      if (j < nc4) { src = c; dst = oc; }
      else {
        j -= nc4;
        if (j >= nd4) return;
        src = d; dst = od;
      }
    }
  }
  float4 v = reinterpret_cast<const float4*>(src)[j];
  ushort4 o;
  o.x = f2bf(v.x); o.y = f2bf(v.y); o.z = f2bf(v.z); o.w = f2bf(v.w);
  reinterpret_cast<ushort4*>(dst)[j] = o;
}

// ---------------- fused RoPE (q then k), in-place, optional scale on q ----------------
__global__ void rope2_kernel(unsigned short* __restrict__ qb, unsigned short* __restrict__ kb,
                             const float* __restrict__ cosb, const float* __restrict__ sinb,
                             int totq, int totk, float qscale) {
  int i = blockIdx.x * blockDim.x + threadIdx.x;
  unsigned short* buf; int nheads; float scale;
  if (i < totq) { buf = qb; nheads = NH; scale = qscale; }
  else {
    i -= totq;
    if (i >= totk) return;
    buf = kb; nheads = NKV; scale = 1.0f;
  }
  int pair = i & 31;
  int rest = i >> 5;
  int s = (rest / nheads) % S_LEN;
  float c = cosb[s * 32 + pair], sn = sinb[s * 32 + pair];
  size_t base = (size_t)rest * HD_ + (size_t)pair * 2;
  float r  = bf2f(buf[base]);
  float im = bf2f(buf[base + 1]);
  buf[base]     = f2bf((r * c - im * sn) * scale);
  buf[base + 1] = f2bf((r * sn + im * c) * scale);
}

// ---------------- fused QKV projection (one dispatch, 768 blocks = 3/CU) ----------------
// m97 structure: 128x128 tile, BK=32, global_load_lds w16, LINEAR LDS.
// blockIdx.x: 0..15 -> Q cols (bf16 row-major), 16..19 -> K cols (bf16 row-major),
//             20..23 -> V cols (bf16 TRANSPOSED out, Vt[KVD][M]).
__global__ __launch_bounds__(256) void gemm_qkv(const unsigned short* __restrict__ A,
                                                const unsigned short* __restrict__ Wq,
                                                const unsigned short* __restrict__ Wk,
                                                const unsigned short* __restrict__ Wv,
                                                unsigned short* __restrict__ Cq,
                                                unsigned short* __restrict__ Ck,
                                                unsigned short* __restrict__ Cvt,
                                                int M, int K) {
  __shared__ alignas(16) short As[128 * 32];
  __shared__ alignas(16) short Bs[128 * 32];
  int tid = threadIdx.x;
  int lane = tid & 63, wid = tid >> 6;
  int bx = blockIdx.x;
  const unsigned short* W; int n0, mode;
  if (bx < 16)      { W = Wq; n0 = bx * 128;        mode = 0; }
  else if (bx < 20) { W = Wk; n0 = (bx - 16) * 128; mode = 1; }
  else              { W = Wv; n0 = (bx - 20) * 128; mode = 2; }
  int m0 = blockIdx.y * 128;
  int wm = (wid >> 1) * 64, wn = (wid & 1) * 64;
  int lrow = lane & 15, lkk = lane >> 4;
  int srow = lane >> 2;
  int scb  = (lane & 3) * 16;
  f32x4 acc[4][4] = {};

  for (int k0 = 0; k0 < K; k0 += 32) {
    __syncthreads();
#pragma unroll
    for (int i = 0; i < 2; ++i) {
      int c = wid * 2 + i;
      int row = c * 16 + srow;
      const char* ga = (const char*)A + ((size_t)(m0 + row) * K + k0) * 2 + scb;
      gl_lds16(ga, (char*)As + c * 1024);
      const char* gw = (const char*)W + ((size_t)(n0 + row) * K + k0) * 2 + scb;
      gl_lds16(gw, (char*)Bs + c * 1024);
    }
    __syncthreads();
    s16x8 af[4], bfr[4];
#pragma unroll
    for (int mi = 0; mi < 4; ++mi) {
      int row = wm + mi * 16 + lrow;
      af[mi] = *reinterpret_cast<const s16x8*>((const char*)As + row * 64 + lkk * 16);
    }
#pragma unroll
    for (int ni = 0; ni < 4; ++ni) {
      int row = wn + ni * 16 + lrow;
      bfr[ni] = *reinterpret_cast<const s16x8*>((const char*)Bs + row * 64 + lkk * 16);
    }
#pragma unroll
    for (int mi = 0; mi < 4; ++mi)
#pragma unroll
      for (int ni = 0; ni < 4; ++ni)
        acc[mi][ni] = __builtin_amdgcn_mfma_f32_16x16x32_bf16(af[mi], bfr[ni], acc[mi][ni], 0, 0, 0);
  }

  if (mode == 2) {
#pragma unroll
    for (int mi = 0; mi < 4; ++mi)
#pragma unroll
      for (int ni = 0; ni < 4; ++ni) {
        int col = n0 + wn + ni * 16 + lrow;
        int mrow = m0 + wm + mi * 16 + lkk * 4;
        ushort4 o;
        o.x = f2bf(acc[mi][ni][0]); o.y = f2bf(acc[mi][ni][1]);
        o.z = f2bf(acc[mi][ni][2]); o.w = f2bf(acc[mi][ni][3]);
        *reinterpret_cast<ushort4*>(Cvt + (size_t)col * M + mrow) = o;
      }
  } else {
    unsigned short* C = (mode == 0) ? Cq : Ck;
    int N = (mode == 0) ? D_MODEL : KVD;
#pragma unroll
    for (int mi = 0; mi < 4; ++mi)
#pragma unroll
      for (int ni = 0; ni < 4; ++ni)
#pragma unroll
        for (int r = 0; r < 4; ++r) {
          int row = m0 + wm + mi * 16 + lkk * 4 + r;
          int col = n0 + wn + ni * 16 + lrow;
          C[(size_t)row * N + col] = f2bf(acc[mi][ni][r]);
        }
  }
}

// ---------------- output projection: m97 structure, f32 out ----------------
__global__ __launch_bounds__(256) void gemm_out(const unsigned short* __restrict__ A,
                                                const unsigned short* __restrict__ W,
                                                float* __restrict__ Cf,
                                                int M, int N, int K) {
  __shared__ alignas(16) short As[128 * 32];
  __shared__ alignas(16) short Bs[128 * 32];
  int tid = threadIdx.x;
  int lane = tid & 63, wid = tid >> 6;
  int m0 = blockIdx.y * 128;
  int n0 = blockIdx.x * 128;
  int wm = (wid >> 1) * 64, wn = (wid & 1) * 64;
  int lrow = lane & 15, lkk = lane >> 4;
  int srow = lane >> 2;
  int scb  = (lane & 3) * 16;
  f32x4 acc[4][4] = {};

  for (int k0 = 0; k0 < K; k0 += 32) {
    __syncthreads();
#pragma unroll
    for (int i = 0; i < 2; ++i) {
      int c = wid * 2 + i;
      int row = c * 16 + srow;
      const char* ga = (const char*)A + ((size_t)(m0 + row) * K + k0) * 2 + scb;
      gl_lds16(ga, (char*)As + c * 1024);
      const char* gw = (const char*)W + ((size_t)(n0 + row) * K + k0) * 2 + scb;
      gl_lds16(gw, (char*)Bs + c * 1024);
    }
    __syncthreads();
    s16x8 af[4], bfr[4];
#pragma unroll
    for (int mi = 0; mi < 4; ++mi) {
      int row = wm + mi * 16 + lrow;
      af[mi] = *reinterpret_cast<const s16x8*>((const char*)As + row * 64 + lkk * 16);
    }
#pragma unroll
    for (int ni = 0; ni < 4; ++ni) {
      int row = wn + ni * 16 + lrow;
      bfr[ni] = *reinterpret_cast<const s16x8*>((const char*)Bs + row * 64 + lkk * 16);
    }
#pragma unroll
    for (int mi = 0; mi < 4; ++mi)
#pragma unroll
      for (int ni = 0; ni < 4; ++ni)
        acc[mi][ni] = __builtin_amdgcn_mfma_f32_16x16x32_bf16(af[mi], bfr[ni], acc[mi][ni], 0, 0, 0);
  }

#pragma unroll
  for (int mi = 0; mi < 4; ++mi)
#pragma unroll
    for (int ni = 0; ni < 4; ++ni)
#pragma unroll
      for (int r = 0; r < 4; ++r) {
        int row = m0 + wm + mi * 16 + lkk * 4 + r;
        int col = n0 + wn + ni * 16 + lrow;
        Cf[(size_t)row * N + col] = acc[mi][ni][r];
      }
}

// ---------------- Flash attention (causal, GQA rep=4), swapped QK^T ----------------
// 8 waves, QBLK=128 (each wave 16 q rows). Balanced pairing x & 15-x -> 34 KV-tiles/block.
// grid (8, B*NH) = 512 blocks = 2/CU. Double-buffered LDS, 1 barrier/tile.
// exp2-domain softmax (Q pre-scaled by 0.125*log2e). T13 defer-max. Wave-uniform
// active-guard skips fully-masked diagonal tiles (also avoids the exp2(0)=1 hazard).
__global__ __launch_bounds__(512) void attn_kernel(const unsigned short* __restrict__ Q,
                                                   const unsigned short* __restrict__ Kb,
                                                   const unsigned short* __restrict__ Vt,
                                                   unsigned short* __restrict__ O) {
  __shared__ alignas(16) short Ks[2][64 * 64];   // [kv][d], 128B rows, XOR (row&7)<<4
  __shared__ alignas(16) short Vs[2][64 * 64];   // [d][kv] (from global Vt), same swizzle

  int tid = threadIdx.x, lane = tid & 63, wid = tid >> 6;   // wid 0..7
  int qi = lane & 15, lk = lane >> 4;
  int bh = blockIdx.y;
  int b = bh / NH, h = bh % NH, kvh = h >> 2;
  size_t bS = (size_t)b * S_LEN;
  int srow = tid >> 3;           // 0..63: one 16B chunk per thread
  int scb  = (tid & 7) * 16;     // byte col within 128B row
  int sw0  = (srow & 7) << 4;

  const char* kbG = (const char*)Kb + (bS * KVD + (size_t)kvh * HD_) * 2;
  const char* vtG = (const char*)Vt + ((size_t)(kvh * 64) * MTOT + bS) * 2;

  s16x8 kr, vr;
  auto GLOAD = [&](int kv0) {
    kr = *reinterpret_cast<const s16x8*>(kbG + (size_t)(kv0 + srow) * (KVD * 2) + scb);
    vr = *reinterpret_cast<const s16x8*>(vtG + (size_t)srow * (MTOT * 2) + kv0 * 2 + scb);
  };
  auto SWRITE = [&](int bf) {
    *reinterpret_cast<s16x8*>((char*)Ks[bf] + srow * 128 + (scb ^ sw0)) = kr;
    *reinterpret_cast<s16x8*>((char*)Vs[bf] + srow * 128 + (scb ^ sw0)) = vr;
  };

#pragma unroll 1
  for (int job = 0; job < 2; ++job) {
    int qtile = (job == 0) ? (int)blockIdx.x : 15 - (int)blockIdx.x;
    int q0 = qtile * 128;
    int nt = 2 * qtile + 2;
    int qlmax = q0 + wid * 16 + 15;   // wave's max q row

    const unsigned short* qptr = Q + (bS + q0 + wid * 16 + qi) * D_MODEL + h * HD_;
    s16x8 qf0 = *reinterpret_cast<const s16x8*>(qptr + lk * 8);
    s16x8 qf1 = *reinterpret_cast<const s16x8*>(qptr + 32 + lk * 8);

    f32x4 o_acc[4] = {};
    float m_run = -3.0e38f, l_run = 0.f;

    GLOAD(0);
    SWRITE(0);
    __syncthreads();
    int cur = 0;

    for (int t = 0; t < nt; ++t) {
      if (t + 1 < nt) GLOAD((t + 1) * 64);   // issue early; latency hides under compute

      if (64 * t <= qlmax) {   // wave-uniform: any unmasked element in this tile?
        const char* kbase = (const char*)Ks[cur];
        const char* vbase = (const char*)Vs[cur];

        // S^T tiles: st[mt][r] = S^T[kv = 64t + mt*16 + 4*lk + r][q = q0 + wid*16 + qi]
        f32x4 st[4];
        __builtin_amdgcn_s_setprio(1);
#pragma unroll
        for (int mt = 0; mt < 4; ++mt) {
          int row = mt * 16 + qi;
          int sw = (row & 7) << 4;
          s16x8 ka0 = *reinterpret_cast<const s16x8*>(kbase + row * 128 + ((lk * 16) ^ sw));
          s16x8 ka1 = *reinterpret_cast<const s16x8*>(kbase + row * 128 + ((64 + lk * 16) ^ sw));
          f32x4 a = {};
          a = __builtin_amdgcn_mfma_f32_16x16x32_bf16(ka0, qf0, a, 0, 0, 0);
          a = __builtin_amdgcn_mfma_f32_16x16x32_bf16(ka1, qf1, a, 0, 0, 0);
          st[mt] = a;
        }
        __builtin_amdgcn_s_setprio(0);

        if (t >= nt - 2) {  // diagonal tiles: mask kv > q (global indices)
          int ql = q0 + wid * 16 + qi;
#pragma unroll
          for (int mt = 0; mt < 4; ++mt)
#pragma unroll
            for (int r = 0; r < 4; ++r) {
              int kvg = 64 * t + mt * 16 + 4 * lk + r;
              if (kvg > ql) st[mt][r] = -3.0e38f;
            }
        }

        // online softmax (exp2 domain); row q=qi lives in lanes {qi, qi+16, qi+32, qi+48}
        float pmax = st[0][0];
#pragma unroll
        for (int mt = 0; mt < 4; ++mt)
#pragma unroll
          for (int r = 0; r < 4; ++r) pmax = fmaxf(pmax, st[mt][r]);
        pmax = fmaxf(pmax, __shfl_xor(pmax, 16, 64));
        pmax = fmaxf(pmax, __shfl_xor(pmax, 32, 64));

        // T13 defer-max: skip rescale while growth <= 8 (P bounded by 2^8)
        if (!__all(pmax <= m_run + 8.0f)) {
          float mnew = fmaxf(m_run, pmax);
          float alpha = fexp2(m_run - mnew);
          m_run = mnew;
          l_run *= alpha;
          float ar[4];
#pragma unroll
          for (int r = 0; r < 4; ++r) ar[r] = __shfl(alpha, 4 * lk + r, 64);
#pragma unroll
          for (int n = 0; n < 4; ++n)
#pragma unroll
            for (int r = 0; r < 4; ++r) o_acc[n][r] *= ar[r];
        }

        float psum = 0.f;
#pragma unroll
        for (int mt = 0; mt < 4; ++mt)
#pragma unroll
          for (int r = 0; r < 4; ++r) {
            float p = fexp2(st[mt][r] - m_run);
            st[mt][r] = p;
            psum += p;
          }
        psum += __shfl_xor(psum, 16, 64);
        psum += __shfl_xor(psum, 32, 64);
        l_run += psum;

        // pack P^T pairs to bf16 (RNE)
        u32 pk[4][2];
#pragma unroll
        for (int mt = 0; mt < 4; ++mt)
#pragma unroll
          for (int w = 0; w < 2; ++w)
            pk[mt][w] = (u32)f2bf(st[mt][2 * w]) | ((u32)f2bf(st[mt][2 * w + 1]) << 16);

        // redistribute P^T -> PV A-frags: pa[ks] word u = P[q=qi][kv=32ks+8lk+2u{,+1}]
        int s0 = qi + 32 * (lk & 1);
        int s2 = s0 + 16;
        bool hiw = lk >= 2;
        s16x8 pa[2];
#pragma unroll
        for (int ks = 0; ks < 2; ++ks) {
          u32 a0 = (u32)__shfl((int)pk[2 * ks][0], s0, 64), b0 = (u32)__shfl((int)pk[2 * ks + 1][0], s0, 64);
          u32 a1 = (u32)__shfl((int)pk[2 * ks][1], s0, 64), b1 = (u32)__shfl((int)pk[2 * ks + 1][1], s0, 64);
          u32 a2 = (u32)__shfl((int)pk[2 * ks][0], s2, 64), b2 = (u32)__shfl((int)pk[2 * ks + 1][0], s2, 64);
          u32 a3 = (u32)__shfl((int)pk[2 * ks][1], s2, 64), b3 = (u32)__shfl((int)pk[2 * ks + 1][1], s2, 64);
          u32x4 wv_;
          wv_[0] = hiw ? b0 : a0; wv_[1] = hiw ? b1 : a1;
          wv_[2] = hiw ? b2 : a2; wv_[3] = hiw ? b3 : a3;
          pa[ks] = __builtin_bit_cast(s16x8, wv_);
        }

        // PV: O[q][d] += P * V ; B-frag from Vs rows (d), contiguous kv
        __builtin_amdgcn_s_setprio(1);
#pragma unroll
        for (int n = 0; n < 4; ++n) {
          int vrw = n * 16 + qi;
          int sw = (vrw & 7) << 4;
          s16x8 vb0 = *reinterpret_cast<const s16x8*>(vbase + vrw * 128 + ((lk * 16) ^ sw));
          s16x8 vb1 = *reinterpret_cast<const s16x8*>(vbase + vrw * 128 + ((64 + lk * 16) ^ sw));
          o_acc[n] = __builtin_amdgcn_mfma_f32_16x16x32_bf16(pa[0], vb0, o_acc[n], 0, 0, 0);
          o_acc[n] = __builtin_amdgcn_mfma_f32_16x16x32_bf16(pa[1], vb1, o_acc[n], 0, 0, 0);
        }
        __builtin_amdgcn_s_setprio(0);
      }

      if (t + 1 < nt) SWRITE(cur ^ 1);   // next tile into other buffer
      __syncthreads();
      cur ^= 1;
    }

    // epilogue: O C-layout row q=4lk+r, col d=16n+qi
    float linv[4];
#pragma unroll
    for (int r = 0; r < 4; ++r) linv[r] = 1.0f / __shfl(l_run, 4 * lk + r, 64);
#pragma unroll
    for (int n = 0; n < 4; ++n)
#pragma unroll
      for (int r = 0; r < 4; ++r) {
        size_t row = bS + q0 + wid * 16 + 4 * lk + r;
        int col = h * HD_ + n * 16 + qi;
        O[row * D_MODEL + col] = f2bf(o_acc[n][r] * linv[r]);
      }
  }
}

// ---------------- launch ----------------
extern "C" void kernel_launch(void* const* d_in, const int* in_sizes, int n_in,
                              void* d_out, int out_size, void* d_ws, size_t ws_size,
                              hipStream_t stream) {
  const float* x  = (const float*)d_in[0];
  const float* fc = (const float*)d_in[1];
  const float* fs = (const float*)d_in[2];
  const float* wq = (const float*)d_in[3];
  const float* wk = (const float*)d_in[4];
  const float* wv = (const float*)d_in[5];
  const float* wo = (const float*)d_in[6];
  float* out = (float*)d_out;

  const size_t nx  = (size_t)BATCH * S_LEN * D_MODEL;
  const size_t nw  = (size_t)D_MODEL * D_MODEL;
  const size_t nwk = (size_t)KVD * D_MODEL;
  const size_t nkv = (size_t)BATCH * S_LEN * KVD;

  char* ws = (char*)d_ws;
  unsigned short* xb  = (unsigned short*)ws;  ws += nx  * 2;
  unsigned short* wqb = (unsigned short*)ws;  ws += nw  * 2;
  unsigned short* wkb = (unsigned short*)ws;  ws += nwk * 2;
  unsigned short* wvb = (unsigned short*)ws;  ws += nwk * 2;
  unsigned short* wob = (unsigned short*)ws;  ws += nw  * 2;
  unsigned short* qb  = (unsigned short*)ws;  ws += nx  * 2;
  unsigned short* kb  = (unsigned short*)ws;  ws += nkv * 2;
  unsigned short* vtb = (unsigned short*)ws;  ws += nkv * 2;   // V^T [KVD][MTOT]
  unsigned short* ab  = (unsigned short*)ws;  ws += nx  * 2;

  cvt_kernel<<<dim3((nx / 4 + 255) / 256), dim3(256), 0, stream>>>(x, xb, nx / 4);
  {
    int na4 = nw / 4, nb4 = nwk / 4, nc4 = nwk / 4, nd4 = nw / 4;
    int tot = na4 + nb4 + nc4 + nd4;
    cvt4_kernel<<<dim3((tot + 255) / 256), dim3(256), 0, stream>>>(wq, wk, wv, wo, wqb, wkb, wvb, wob,
                                                                   na4, nb4, nc4, nd4);
  }

  const int M = BATCH * S_LEN;  // 4096
  gemm_qkv<<<dim3(24, M / 128), dim3(256), 0, stream>>>(xb, wqb, wkb, wvb, qb, kb, vtb, M, D_MODEL);

  {
    int totq = BATCH * S_LEN * NH * 32;
    int totk = BATCH * S_LEN * NKV * 32;
    // 0.125 * log2(e): QK^T lands directly in exp2 domain
    rope2_kernel<<<dim3((totq + totk + 255) / 256), dim3(256), 0, stream>>>(qb, kb, fc, fs, totq, totk,
                                                                            0.18033688011112042f);
  }

  attn_kernel<<<dim3(8, BATCH * NH), dim3(512), 0, stream>>>(qb, kb, vtb, ab);

  gemm_out<<<dim3(D_MODEL / 128, M / 128), dim3(256), 0, stream>>>(ab, wob, out, M, D_MODEL, D_MODEL);
}